// Round 1
// baseline (86.024 us; speedup 1.0000x reference)
//
#include <hip/hip_runtime.h>
#include <hip/hip_bf16.h>

// Problem: B=32, N=4096, D=256, F=256
//   x = relu(A @ W + bias)            A:[B,F] W:[F,N] -> x:[B,N]
//   mask = x > threshold
//   out[b] = stable-compact(raw_input[b] rows where mask), zero-padded to N.

#define BB 32
#define NN 4096
#define DD 256
#define FF 256

// ---------------- Kernel 1: mask + stable exclusive scan -> order, count ----
// One block per batch. 1024 threads, each owns 4 consecutive n (n0=4*tid).
__global__ __launch_bounds__(1024) void mask_scan_kernel(
    const float* __restrict__ A,      // [B,F]
    const float* __restrict__ W,      // [F,N]
    const float* __restrict__ bias,   // [N]
    const float* __restrict__ thr_p,  // [1]
    int* __restrict__ order,          // [B,N]
    int* __restrict__ count)          // [B]
{
    const int b   = blockIdx.x;
    const int tid = threadIdx.x;

    __shared__ float a_sh[FF];
    __shared__ int   wsum[16];

    if (tid < FF) a_sh[tid] = A[b * FF + tid];
    __syncthreads();

    const float thr = thr_p[0];
    const int n0 = tid * 4;

    // 4 dot products, accumulate in double to stay close to the true value
    // (mask flips vs the f32 reference shift whole rows -> huge absmax).
    double acc0 = 0.0, acc1 = 0.0, acc2 = 0.0, acc3 = 0.0;
    const float* wp = W + n0;
    #pragma unroll 4
    for (int f = 0; f < FF; ++f) {
        float4 w4 = *reinterpret_cast<const float4*>(wp + (size_t)f * NN);
        double a = (double)a_sh[f];
        acc0 += a * (double)w4.x;
        acc1 += a * (double)w4.y;
        acc2 += a * (double)w4.z;
        acc3 += a * (double)w4.w;
    }
    float4 bi = *reinterpret_cast<const float4*>(bias + n0);
    float v0 = (float)acc0 + bi.x;
    float v1 = (float)acc1 + bi.y;
    float v2 = (float)acc2 + bi.z;
    float v3 = (float)acc3 + bi.w;

    int m0 = (fmaxf(v0, 0.f) > thr) ? 1 : 0;
    int m1 = (fmaxf(v1, 0.f) > thr) ? 1 : 0;
    int m2 = (fmaxf(v2, 0.f) > thr) ? 1 : 0;
    int m3 = (fmaxf(v3, 0.f) > thr) ? 1 : 0;

    int s = m0 + m1 + m2 + m3;

    // wave(64)-level inclusive scan
    const int lane = tid & 63;
    const int wid  = tid >> 6;
    int incl = s;
    #pragma unroll
    for (int d = 1; d < 64; d <<= 1) {
        int t = __shfl_up(incl, d, 64);
        if (lane >= d) incl += t;
    }
    if (lane == 63) wsum[wid] = incl;
    __syncthreads();
    if (tid == 0) {
        int run = 0;
        #pragma unroll
        for (int i = 0; i < 16; ++i) { int t = wsum[i]; wsum[i] = run; run += t; }
        count[b] = run;
    }
    __syncthreads();

    int base = wsum[wid] + (incl - s);   // stable exclusive prefix for n0
    int* ob = order + b * NN;
    if (m0) ob[base++] = n0;
    if (m1) ob[base++] = n0 + 1;
    if (m2) ob[base++] = n0 + 2;
    if (m3) ob[base++] = n0 + 3;
}

// ---------------- Kernel 2: gather rows / zero tail -------------------------
// Grid (N/4, B), 256 threads = 4 waves; wave w handles dst row j=4*bx+w.
// 64 lanes x float4 = 1024 B = one full row of D=256 floats.
__global__ __launch_bounds__(256) void gather_kernel(
    const float* __restrict__ raw,    // [B,N,D]
    const int* __restrict__ order,    // [B,N]
    const int* __restrict__ count,    // [B]
    float* __restrict__ out)          // [B,N,D]
{
    const int b    = blockIdx.y;
    const int wid  = threadIdx.x >> 6;
    const int lane = threadIdx.x & 63;
    const int j    = blockIdx.x * 4 + wid;

    const int cnt = count[b];
    float4* dst = reinterpret_cast<float4*>(out + ((size_t)b * NN + j) * DD) + lane;
    if (j < cnt) {
        const int src = order[b * NN + j];
        const float4* sp =
            reinterpret_cast<const float4*>(raw + ((size_t)b * NN + src) * DD) + lane;
        *dst = *sp;
    } else {
        *dst = make_float4(0.f, 0.f, 0.f, 0.f);
    }
}

extern "C" void kernel_launch(void* const* d_in, const int* in_sizes, int n_in,
                              void* d_out, int out_size, void* d_ws, size_t ws_size,
                              hipStream_t stream) {
    const float* raw  = (const float*)d_in[0];   // [B,N,D]
    const float* A    = (const float*)d_in[1];   // [B,F]
    const float* W    = (const float*)d_in[2];   // [F,N]
    const float* bias = (const float*)d_in[3];   // [N]
    const float* thr  = (const float*)d_in[4];   // [1]
    float* out = (float*)d_out;

    int*   order = (int*)d_ws;                      // B*N ints = 512 KB
    int*   count = (int*)d_ws + (size_t)BB * NN;    // B ints

    mask_scan_kernel<<<BB, 1024, 0, stream>>>(A, W, bias, thr, order, count);
    gather_kernel<<<dim3(NN / 4, BB), 256, 0, stream>>>(raw, order, count, out);
}

// Round 2
// 62.199 us; speedup vs baseline: 1.3830x; 1.3830x over previous
//
#include <hip/hip_runtime.h>
#include <hip/hip_bf16.h>
#include <stdint.h>

// Problem: B=32, N=4096, D=256, F=256
//   x = relu(A @ W + bias)            A:[B,F] W:[F,N] -> x:[B,N]
//   mask = x > threshold
//   out[b] = stable-compact(raw_input[b] rows where mask), zero-padded to N.

#define BB 32
#define NN 4096
#define DD 256
#define FF 256
#define COLS 16   // W columns per block in mask_kernel

// ---------------- Kernel 1: tiny GEMM -> byte mask --------------------------
// Grid N/COLS = 256 blocks. Each block: COLS columns x all 32 batches.
// W is read exactly once overall (4 MB); A staged in LDS (32 KB).
__global__ __launch_bounds__(256) void mask_kernel(
    const float* __restrict__ A,      // [B,F]
    const float* __restrict__ W,      // [F,N]
    const float* __restrict__ bias,   // [N]
    const float* __restrict__ thr_p,  // [1]
    uint8_t* __restrict__ mask)       // [B,N]
{
    __shared__ float a_sh[BB * FF];      // 32 KB, [b][f]
    __shared__ float w_sh[FF * COLS];    // 16 KB, [f][c]

    const int t  = threadIdx.x;
    const int n0 = blockIdx.x * COLS;

    // A: contiguous copy (8192 floats)
    for (int i = t; i < BB * FF; i += 256) a_sh[i] = A[i];
    // W chunk: rows f=0..255, cols n0..n0+COLS-1
    for (int i = t; i < FF * COLS; i += 256) {
        int f = i / COLS, c = i % COLS;
        w_sh[i] = W[(size_t)f * NN + n0 + c];
    }
    __syncthreads();

    const float thr = thr_p[0];

    // BB*COLS = 512 outputs, 2 per thread.
    for (int p = t; p < BB * COLS; p += 256) {
        const int b = p / COLS, c = p % COLS;
        const float* ap = a_sh + b * FF;
        const float* wp = w_sh + c;
        // f64 accumulation: mask flips vs the f32 reference shift whole rows.
        double acc0 = 0.0, acc1 = 0.0, acc2 = 0.0, acc3 = 0.0;
        #pragma unroll 4
        for (int f = 0; f < FF; f += 4) {
            acc0 += (double)ap[f + 0] * (double)wp[(f + 0) * COLS];
            acc1 += (double)ap[f + 1] * (double)wp[(f + 1) * COLS];
            acc2 += (double)ap[f + 2] * (double)wp[(f + 2) * COLS];
            acc3 += (double)ap[f + 3] * (double)wp[(f + 3) * COLS];
        }
        float v = (float)((acc0 + acc1) + (acc2 + acc3)) + bias[n0 + c];
        mask[(size_t)b * NN + n0 + c] = (fmaxf(v, 0.f) > thr) ? 1 : 0;
    }
}

// ---------------- Kernel 2: per-batch stable scan -> order, count -----------
// One block per batch, 1024 threads, each owns 4 consecutive n.
__global__ __launch_bounds__(1024) void scan_kernel(
    const uint8_t* __restrict__ mask, // [B,N]
    int* __restrict__ order,          // [B,N]
    int* __restrict__ count)          // [B]
{
    const int b   = blockIdx.x;
    const int tid = threadIdx.x;
    __shared__ int wsum[16];

    const uchar4 m4 = reinterpret_cast<const uchar4*>(mask + (size_t)b * NN)[tid];
    const int m0 = m4.x, m1 = m4.y, m2 = m4.z, m3 = m4.w;
    const int s  = m0 + m1 + m2 + m3;
    const int n0 = tid * 4;

    // wave(64)-level inclusive scan
    const int lane = tid & 63;
    const int wid  = tid >> 6;
    int incl = s;
    #pragma unroll
    for (int d = 1; d < 64; d <<= 1) {
        int t = __shfl_up(incl, d, 64);
        if (lane >= d) incl += t;
    }
    if (lane == 63) wsum[wid] = incl;
    __syncthreads();
    if (tid == 0) {
        int run = 0;
        #pragma unroll
        for (int i = 0; i < 16; ++i) { int t = wsum[i]; wsum[i] = run; run += t; }
        count[b] = run;
    }
    __syncthreads();

    int base = wsum[wid] + (incl - s);   // stable exclusive prefix for n0
    int* ob = order + (size_t)b * NN;
    if (m0) ob[base++] = n0;
    if (m1) ob[base++] = n0 + 1;
    if (m2) ob[base++] = n0 + 2;
    if (m3) ob[base++] = n0 + 3;
}

// ---------------- Kernel 3: gather rows / zero tail -------------------------
// Grid (N/4, B), 256 threads = 4 waves; wave w handles dst row j=4*bx+w.
// 64 lanes x float4 = 1024 B = one full row of D=256 floats.
__global__ __launch_bounds__(256) void gather_kernel(
    const float* __restrict__ raw,    // [B,N,D]
    const int* __restrict__ order,    // [B,N]
    const int* __restrict__ count,    // [B]
    float* __restrict__ out)          // [B,N,D]
{
    const int b    = blockIdx.y;
    const int wid  = threadIdx.x >> 6;
    const int lane = threadIdx.x & 63;
    const int j    = blockIdx.x * 4 + wid;

    const int cnt = count[b];
    float4* dst = reinterpret_cast<float4*>(out + ((size_t)b * NN + j) * DD) + lane;
    if (j < cnt) {
        const int src = order[(size_t)b * NN + j];
        const float4* sp =
            reinterpret_cast<const float4*>(raw + ((size_t)b * NN + src) * DD) + lane;
        *dst = *sp;
    } else {
        *dst = make_float4(0.f, 0.f, 0.f, 0.f);
    }
}

extern "C" void kernel_launch(void* const* d_in, const int* in_sizes, int n_in,
                              void* d_out, int out_size, void* d_ws, size_t ws_size,
                              hipStream_t stream) {
    const float* raw  = (const float*)d_in[0];   // [B,N,D]
    const float* A    = (const float*)d_in[1];   // [B,F]
    const float* W    = (const float*)d_in[2];   // [F,N]
    const float* bias = (const float*)d_in[3];   // [N]
    const float* thr  = (const float*)d_in[4];   // [1]
    float* out = (float*)d_out;

    uint8_t* mask  = (uint8_t*)d_ws;                          // B*N bytes = 128 KB
    int*     order = (int*)((char*)d_ws + (size_t)BB * NN);   // B*N ints  = 512 KB
    int*     count = order + (size_t)BB * NN;                 // B ints

    mask_kernel<<<NN / COLS, 256, 0, stream>>>(A, W, bias, thr, mask);
    scan_kernel<<<BB, 1024, 0, stream>>>(mask, order, count);
    gather_kernel<<<dim3(NN / 4, BB), 256, 0, stream>>>(raw, order, count, out);
}

// Round 3
// 60.082 us; speedup vs baseline: 1.4318x; 1.0352x over previous
//
#include <hip/hip_runtime.h>
#include <hip/hip_bf16.h>
#include <stdint.h>

// Problem: B=32, N=4096, D=256, F=256
//   x = relu(A @ W + bias)            A:[B,F] W:[F,N] -> x:[B,N]
//   mask = x > threshold
//   out[b] = stable-compact(raw_input[b] rows where mask), zero-padded to N.

#define BB 32
#define NN 4096
#define DD 256
#define FF 256
#define COLS 16            // W columns per block in mask_kernel
#define CH (NN / COLS)     // 256 chunks
#define ASTRIDE (FF + 4)   // padded LDS stride (260 floats, 16B-aligned, bank-spread)

typedef float f4 __attribute__((ext_vector_type(4)));

// ---------------- Kernel 1: tiny GEMM -> packed 16-bit masks ----------------
// Grid CH=256 blocks x 256 threads. Block owns 16 columns x all 32 batches.
// W read exactly once from HBM (4 MB). A (32 KB) + W-chunk staged in LDS,
// both read as float4 (b128). f64 accumulation: a mask flip vs the f32
// reference shifts whole output rows -> absmax ~5. f64 keeps us exact.
__global__ __launch_bounds__(256) void mask_kernel(
    const float* __restrict__ A,      // [B,F]
    const float* __restrict__ W,      // [F,N]
    const float* __restrict__ bias,   // [N]
    const float* __restrict__ thr_p,  // [1]
    uint16_t* __restrict__ bits)      // [B,CH]
{
    __shared__ float a_sh[BB * ASTRIDE];    // [b][f], stride 260
    __shared__ float wT[COLS * ASTRIDE];    // [c][f], stride 260

    const int t     = threadIdx.x;
    const int chunk = blockIdx.x;
    const int n0    = chunk * COLS;

    for (int i = t; i < BB * FF; i += 256) {
        int b = i >> 8, f = i & 255;
        a_sh[b * ASTRIDE + f] = A[i];
    }
    for (int i = t; i < FF * COLS; i += 256) {
        int f = i >> 4, c = i & 15;
        wT[c * ASTRIDE + f] = W[(size_t)f * NN + n0 + c];
    }
    __syncthreads();

    const float thr = thr_p[0];
    const int c  = t & 15;
    const int b1 = t >> 4;        // 0..15
    const int b2 = b1 + 16;       // 16..31

    const f4* a1p = reinterpret_cast<const f4*>(a_sh + b1 * ASTRIDE);
    const f4* a2p = reinterpret_cast<const f4*>(a_sh + b2 * ASTRIDE);
    const f4* wp  = reinterpret_cast<const f4*>(wT   + c  * ASTRIDE);

    double s0 = 0.0, s1 = 0.0, s2 = 0.0, s3 = 0.0;
    #pragma unroll 8
    for (int fs = 0; fs < FF / 4; ++fs) {
        f4 w4 = wp[fs];
        f4 a1 = a1p[fs];
        f4 a2 = a2p[fs];
        s0 = fma((double)a1.x, (double)w4.x, s0);
        s0 = fma((double)a1.y, (double)w4.y, s0);
        s1 = fma((double)a1.z, (double)w4.z, s1);
        s1 = fma((double)a1.w, (double)w4.w, s1);
        s2 = fma((double)a2.x, (double)w4.x, s2);
        s2 = fma((double)a2.y, (double)w4.y, s2);
        s3 = fma((double)a2.z, (double)w4.z, s3);
        s3 = fma((double)a2.w, (double)w4.w, s3);
    }
    const float bi = bias[n0 + c];
    const float v1 = (float)(s0 + s1) + bi;
    const float v2 = (float)(s2 + s3) + bi;
    const int m1 = (fmaxf(v1, 0.f) > thr) ? 1 : 0;
    const int m2 = (fmaxf(v2, 0.f) > thr) ? 1 : 0;

    // Ballot-pack: lane l of each wave has c=l&15, batch-group g=l>>4.
    unsigned long long bal1 = __ballot(m1);
    unsigned long long bal2 = __ballot(m2);
    if (c == 0) {
        const int g = (t & 63) >> 4;   // == b1 & 3
        bits[b1 * CH + chunk] = (uint16_t)((bal1 >> (16 * g)) & 0xFFFF);
        bits[b2 * CH + chunk] = (uint16_t)((bal2 >> (16 * g)) & 0xFFFF);
    }
}

// ---------------- Kernel 2: per-batch stable scan -> order, count -----------
// One block per batch, 256 threads; thread t owns chunk t (16 columns).
__global__ __launch_bounds__(256) void scan_kernel(
    const uint16_t* __restrict__ bits, // [B,CH]
    int* __restrict__ order,           // [B,N]
    int* __restrict__ count)           // [B]
{
    const int b = blockIdx.x;
    const int t = threadIdx.x;
    __shared__ int wsum[4];

    unsigned m = bits[b * CH + t];
    const int s = __popc(m);

    const int lane = t & 63;
    const int wid  = t >> 6;
    int incl = s;
    #pragma unroll
    for (int d = 1; d < 64; d <<= 1) {
        int x = __shfl_up(incl, d, 64);
        if (lane >= d) incl += x;
    }
    if (lane == 63) wsum[wid] = incl;
    __syncthreads();
    if (t == 0) {
        int run = 0;
        #pragma unroll
        for (int i = 0; i < 4; ++i) { int x = wsum[i]; wsum[i] = run; run += x; }
        count[b] = run;
    }
    __syncthreads();

    int base = wsum[wid] + (incl - s);   // stable exclusive prefix
    int* ob = order + (size_t)b * NN + base;
    const int n0 = t * COLS;
    while (m) {
        *ob++ = n0 + (__ffs(m) - 1);
        m &= m - 1;
    }
}

// ---------------- Kernel 3: gather rows / zero tail -------------------------
// Grid (N/8, B), 256 threads = 4 waves; wave w handles dst rows j0, j0+1.
// 64 lanes x float4 = 1024 B = one full row. Nontemporal: streaming, no reuse.
__global__ __launch_bounds__(256) void gather_kernel(
    const float* __restrict__ raw,    // [B,N,D]
    const int* __restrict__ order,    // [B,N]
    const int* __restrict__ count,    // [B]
    float* __restrict__ out)          // [B,N,D]
{
    const int b    = blockIdx.y;
    const int wid  = threadIdx.x >> 6;
    const int lane = threadIdx.x & 63;
    const int j0   = blockIdx.x * 8 + wid * 2;

    const int cnt = count[b];
    const int* ob = order + (size_t)b * NN;
    const f4* rawp = reinterpret_cast<const f4*>(raw);
    f4* outp = reinterpret_cast<f4*>(out);

    f4 r0 = {0.f, 0.f, 0.f, 0.f};
    f4 r1 = {0.f, 0.f, 0.f, 0.f};
    if (j0 < cnt) {
        const int src = ob[j0];
        r0 = __builtin_nontemporal_load(rawp + ((size_t)b * NN + src) * (DD / 4) + lane);
    }
    if (j0 + 1 < cnt) {
        const int src = ob[j0 + 1];
        r1 = __builtin_nontemporal_load(rawp + ((size_t)b * NN + src) * (DD / 4) + lane);
    }
    __builtin_nontemporal_store(r0, outp + ((size_t)b * NN + j0)     * (DD / 4) + lane);
    __builtin_nontemporal_store(r1, outp + ((size_t)b * NN + j0 + 1) * (DD / 4) + lane);
}

extern "C" void kernel_launch(void* const* d_in, const int* in_sizes, int n_in,
                              void* d_out, int out_size, void* d_ws, size_t ws_size,
                              hipStream_t stream) {
    const float* raw  = (const float*)d_in[0];   // [B,N,D]
    const float* A    = (const float*)d_in[1];   // [B,F]
    const float* W    = (const float*)d_in[2];   // [F,N]
    const float* bias = (const float*)d_in[3];   // [N]
    const float* thr  = (const float*)d_in[4];   // [1]
    float* out = (float*)d_out;

    uint16_t* bits  = (uint16_t*)d_ws;                        // 16 KB
    int*      order = (int*)((char*)d_ws + 65536);            // 512 KB
    int*      count = order + (size_t)BB * NN;                // 128 B

    mask_kernel<<<CH, 256, 0, stream>>>(A, W, bias, thr, bits);
    scan_kernel<<<BB, 256, 0, stream>>>(bits, order, count);
    gather_kernel<<<dim3(NN / 8, BB), 256, 0, stream>>>(raw, order, count, out);
}